// Round 1
// 467.945 us; speedup vs baseline: 1.1871x; 1.1871x over previous
//
#include <hip/hip_runtime.h>
#include <math.h>

#define N_NODES 50000
#define N_EDGES 800000
#define NPAD 50176
#define HSTR 224   // hbuf row stride in HALFS: 448 B = exactly 4 x 128B sectors per row fetch
// ecsbuf (NPAD+2 ints, ecsbuf[0]=0): counts at ecsbuf[1+d] (k_hist); post-scan
// ecsbuf[1+d] = start(d), never mutated again (rank-based fill).
// Readers: start(n) = ecsbuf[n+1], end(n) = ecsbuf[n+2].

typedef __attribute__((ext_vector_type(8))) short short8;
typedef __attribute__((ext_vector_type(4))) float f32x4;
typedef __attribute__((ext_vector_type(4))) _Float16 half4;

// ---------------- helpers ----------------

__device__ __forceinline__ float fast_tanh(float x) {
    float e = __expf(2.0f * x);
    float r = __builtin_amdgcn_rcpf(e + 1.0f);
    return 1.0f - 2.0f * r;
}

__device__ __forceinline__ unsigned short rne_bf16(float x) {
    unsigned u = __builtin_bit_cast(unsigned, x);
    return (unsigned short)((u + 0x7FFFu + ((u >> 16) & 1u)) >> 16);
}

__device__ __forceinline__ void split_bf16(float x, unsigned short& hi, unsigned short& lo) {
    hi = rne_bf16(x);
    float hf = __builtin_bit_cast(float, (unsigned)hi << 16);
    lo = rne_bf16(x - hf);
}

__device__ __forceinline__ f32x4 mfma16(short8 a, short8 b, f32x4 c) {
    return __builtin_amdgcn_mfma_f32_16x16x32_bf16(a, b, c, 0, 0, 0);
}

__device__ __forceinline__ void wsplit_one(const float* __restrict__ W, int KIN, int LDA,
                                           unsigned short* __restrict__ WT_hi,
                                           unsigned short* __restrict__ WT_lo, int idx) {
    int n = idx / LDA;
    int k = idx - n * LDA;
    float v = (n < 220 && k < KIN) ? W[k * 220 + n] : 0.f;
    unsigned short hi, lo;
    split_bf16(v, hi, lo);
    WT_hi[idx] = hi;
    WT_lo[idx] = lo;
}

// ---------------- CSR build ----------------

// partitioned launch: [0,3125) histogram + per-edge rank; [3125,3545) weight splits
__global__ void k_hist_wsplit(const int* __restrict__ ei, int* __restrict__ deg_out,
                              int* __restrict__ ecsbuf, int* __restrict__ rank,
                              const float* __restrict__ W0, const float* __restrict__ W1,
                              const float* __restrict__ W2,
                              unsigned short* __restrict__ wt0h, unsigned short* __restrict__ wt0l,
                              unsigned short* __restrict__ wt1h, unsigned short* __restrict__ wt1l,
                              unsigned short* __restrict__ wt2h, unsigned short* __restrict__ wt2l) {
    int bx = blockIdx.x;
    if (bx < 3125) {
        int e = bx * 256 + threadIdx.x;
        if (e < N_EDGES) {
            atomicAdd(&deg_out[ei[e]], 1);
            rank[e] = atomicAdd(&ecsbuf[1 + ei[N_EDGES + e]], 1);
        }
    } else if (bx < 3153) {
        int idx = (bx - 3125) * 256 + threadIdx.x;          // 224*32 = 7168
        if (idx < 224 * 32) wsplit_one(W0, 22, 32, wt0h, wt0l, idx);
    } else if (bx < 3349) {
        int idx = (bx - 3153) * 256 + threadIdx.x;          // 224*224 = 50176
        wsplit_one(W1, 220, 224, wt1h, wt1l, idx);
    } else {
        int idx = (bx - 3349) * 256 + threadIdx.x;
        wsplit_one(W2, 220, 224, wt2h, wt2l, idx);
    }
}

__global__ void k_scan1(const int* __restrict__ in, int* __restrict__ out,
                        int* __restrict__ bsum, int n) {
    __shared__ int s[256];
    int i = blockIdx.x * 256 + threadIdx.x;
    int v = (i < n) ? in[i] : 0;
    s[threadIdx.x] = v;
    __syncthreads();
    for (int off = 1; off < 256; off <<= 1) {
        int t = (threadIdx.x >= off) ? s[threadIdx.x - off] : 0;
        __syncthreads();
        s[threadIdx.x] += t;
        __syncthreads();
    }
    if (i < n) out[i] = s[threadIdx.x] - v;   // exclusive
    if (threadIdx.x == 255 && bsum) bsum[blockIdx.x] = s[255];
}

__global__ void k_scan_mid(int* __restrict__ a, int n) {
    __shared__ int s[256];
    __shared__ int carry;
    if (threadIdx.x == 0) carry = 0;
    for (int base = 0; base < n; base += 256) {
        int i = base + threadIdx.x;
        int v = (i < n) ? a[i] : 0;
        s[threadIdx.x] = v;
        __syncthreads();
        for (int off = 1; off < 256; off <<= 1) {
            int t = (threadIdx.x >= off) ? s[threadIdx.x - off] : 0;
            __syncthreads();
            s[threadIdx.x] += t;
            __syncthreads();
        }
        int c = carry;
        if (i < n) a[i] = s[threadIdx.x] - v + c;
        __syncthreads();
        if (threadIdx.x == 0) carry = c + s[255];
        __syncthreads();
    }
}

__global__ void k_scan3(int* __restrict__ out, const int* __restrict__ bscan, int n) {
    int i = blockIdx.x * 256 + threadIdx.x;
    if (i < n) out[i] += bscan[blockIdx.x];
}

// fused post-scan: [0,196) invsqrt | [196,3321) atomic-free fill | [3321,5470) prescale xs
__global__ void k_post_scan(const int* __restrict__ ei, const int* __restrict__ ecsbuf,
                            const int* __restrict__ rank, const int* __restrict__ deg_out,
                            const float* __restrict__ x,
                            float* __restrict__ inv_out, float* __restrict__ inv_in,
                            int* __restrict__ src_sorted, float* __restrict__ xs) {
    int bx = blockIdx.x;
    if (bx < 196) {
        int n = bx * 256 + threadIdx.x;
        if (n >= N_NODES) return;
        int di = ecsbuf[n + 2] - ecsbuf[n + 1];
        int a = deg_out[n]; if (a < 1) a = 1;
        if (di < 1) di = 1;
        inv_out[n] = 1.0f / sqrtf((float)a);
        inv_in[n]  = 1.0f / sqrtf((float)di);
    } else if (bx < 3321) {
        int e = (bx - 196) * 256 + threadIdx.x;
        if (e < N_EDGES) {
            int d = ei[N_EDGES + e];
            src_sorted[ecsbuf[1 + d] + rank[e]] = ei[e];
        }
    } else {
        int idx = (bx - 3321) * 256 + threadIdx.x;   // n*11 + f2
        if (idx >= N_NODES * 11) return;
        int n = idx / 11;
        int f2 = idx - n * 11;
        int a = deg_out[n]; if (a < 1) a = 1;
        float sc = 1.0f / sqrtf((float)a);
        float2 v = *(const float2*)&x[n * 22 + f2 * 2];
        v.x *= sc; v.y *= sc;
        *(float2*)&xs[n * 22 + f2 * 2] = v;
    }
}

// ---------------- aggregation ----------------

// layer 0: gather pre-scaled xs (width 22), *inv_in, split to bf16 A (K pad 32).
__global__ void k_agg22_split(const float* __restrict__ xs,
                              const int* __restrict__ ecsbuf, const int* __restrict__ srcs,
                              const float* __restrict__ inv_in,
                              unsigned short* __restrict__ A_hi, unsigned short* __restrict__ A_lo) {
    int idx = blockIdx.x * 256 + threadIdx.x;
    int n = idx >> 4, f2 = idx & 15;
    if (n >= N_NODES) return;
    float ax = 0.f, ay = 0.f;
    if (f2 <= 10) {
        const float2* xb = (const float2*)(xs) + f2;
        int e = ecsbuf[n + 1], end = ecsbuf[n + 2];
        for (; e + 3 < end; e += 4) {
            int s0 = srcs[e], s1 = srcs[e + 1], s2 = srcs[e + 2], s3 = srcs[e + 3];
            float2 v0 = xb[s0 * 11], v1 = xb[s1 * 11];
            float2 v2 = xb[s2 * 11], v3 = xb[s3 * 11];
            ax += (v0.x + v1.x) + (v2.x + v3.x);
            ay += (v0.y + v1.y) + (v2.y + v3.y);
        }
        for (; e < end; ++e) {
            float2 v0 = xb[srcs[e] * 11];
            ax += v0.x;
            ay += v0.y;
        }
        float si = inv_in[n];
        ax *= si; ay *= si;
    }
    ushort2 h2, l2;
    split_bf16(ax, h2.x, l2.x);
    split_bf16(ay, h2.y, l2.y);
    *(ushort2*)&A_hi[n * 32 + f2 * 2] = h2;
    *(ushort2*)&A_lo[n * 32 + f2 * 2] = l2;
}

// width-220 gather (h stored fp16, row = 224 halfs = 448 B = 4 sectors) + *inv_in
// -> split bf16 A.  One node per 64-lane group; lanes 0..54 own 4 features
// (8 B half4 loads); 8 loads in flight; fp32 accumulation (fp16 rne storage
// error ~2^-12 rel on |v|<1 -> final absmax ~5e-5, see round theory).
__global__ __launch_bounds__(256) void k_agg220_split(const _Float16* __restrict__ h,
                                                      const int* __restrict__ ecsbuf,
                                                      const int* __restrict__ srcs,
                                                      const float* __restrict__ inv_in,
                                                      unsigned short* __restrict__ A_hi,
                                                      unsigned short* __restrict__ A_lo) {
    int lane = threadIdx.x & 63;
    int n = blockIdx.x * 4 + (threadIdx.x >> 6);
    if (n >= N_NODES || lane >= 56) return;   // no barriers; early-exit safe
    size_t ob = (size_t)n * 224 + lane * 4;
    if (lane == 55) {                          // K-pad columns 220..223 = 0
        ushort4 z = {0, 0, 0, 0};
        *(ushort4*)&A_hi[ob] = z;
        *(ushort4*)&A_lo[ob] = z;
        return;
    }
    int f4 = lane * 4;
    const _Float16* hb = h + f4;
    int e = ecsbuf[n + 1], end = ecsbuf[n + 2];
    float4 a0 = {0,0,0,0}, a1 = {0,0,0,0}, a2 = {0,0,0,0}, a3 = {0,0,0,0};
    for (; e + 7 < end; e += 8) {
        int s0 = srcs[e],     s1 = srcs[e + 1], s2 = srcs[e + 2], s3 = srcs[e + 3];
        int s4 = srcs[e + 4], s5 = srcs[e + 5], s6 = srcs[e + 6], s7 = srcs[e + 7];
        half4 v0 = *(const half4*)(hb + (size_t)s0 * HSTR);
        half4 v1 = *(const half4*)(hb + (size_t)s1 * HSTR);
        half4 v2 = *(const half4*)(hb + (size_t)s2 * HSTR);
        half4 v3 = *(const half4*)(hb + (size_t)s3 * HSTR);
        half4 v4 = *(const half4*)(hb + (size_t)s4 * HSTR);
        half4 v5 = *(const half4*)(hb + (size_t)s5 * HSTR);
        half4 v6 = *(const half4*)(hb + (size_t)s6 * HSTR);
        half4 v7 = *(const half4*)(hb + (size_t)s7 * HSTR);
        a0.x += (float)v0.x; a0.y += (float)v0.y; a0.z += (float)v0.z; a0.w += (float)v0.w;
        a1.x += (float)v1.x; a1.y += (float)v1.y; a1.z += (float)v1.z; a1.w += (float)v1.w;
        a2.x += (float)v2.x; a2.y += (float)v2.y; a2.z += (float)v2.z; a2.w += (float)v2.w;
        a3.x += (float)v3.x; a3.y += (float)v3.y; a3.z += (float)v3.z; a3.w += (float)v3.w;
        a0.x += (float)v4.x; a0.y += (float)v4.y; a0.z += (float)v4.z; a0.w += (float)v4.w;
        a1.x += (float)v5.x; a1.y += (float)v5.y; a1.z += (float)v5.z; a1.w += (float)v5.w;
        a2.x += (float)v6.x; a2.y += (float)v6.y; a2.z += (float)v6.z; a2.w += (float)v6.w;
        a3.x += (float)v7.x; a3.y += (float)v7.y; a3.z += (float)v7.z; a3.w += (float)v7.w;
    }
    for (; e + 3 < end; e += 4) {
        int s0 = srcs[e], s1 = srcs[e + 1], s2 = srcs[e + 2], s3 = srcs[e + 3];
        half4 v0 = *(const half4*)(hb + (size_t)s0 * HSTR);
        half4 v1 = *(const half4*)(hb + (size_t)s1 * HSTR);
        half4 v2 = *(const half4*)(hb + (size_t)s2 * HSTR);
        half4 v3 = *(const half4*)(hb + (size_t)s3 * HSTR);
        a0.x += (float)v0.x; a0.y += (float)v0.y; a0.z += (float)v0.z; a0.w += (float)v0.w;
        a1.x += (float)v1.x; a1.y += (float)v1.y; a1.z += (float)v1.z; a1.w += (float)v1.w;
        a2.x += (float)v2.x; a2.y += (float)v2.y; a2.z += (float)v2.z; a2.w += (float)v2.w;
        a3.x += (float)v3.x; a3.y += (float)v3.y; a3.z += (float)v3.z; a3.w += (float)v3.w;
    }
    for (; e < end; ++e) {
        half4 v = *(const half4*)(hb + (size_t)srcs[e] * HSTR);
        a0.x += (float)v.x; a0.y += (float)v.y; a0.z += (float)v.z; a0.w += (float)v.w;
    }
    float sc = inv_in[n];
    float4 t;
    t.x = ((a0.x + a1.x) + (a2.x + a3.x)) * sc;
    t.y = ((a0.y + a1.y) + (a2.y + a3.y)) * sc;
    t.z = ((a0.z + a1.z) + (a2.z + a3.z)) * sc;
    t.w = ((a0.w + a1.w) + (a2.w + a3.w)) * sc;
    ushort4 h4, l4;
    split_bf16(t.x, h4.x, l4.x);
    split_bf16(t.y, h4.y, l4.y);
    split_bf16(t.z, h4.z, l4.z);
    split_bf16(t.w, h4.w, l4.w);
    *(ushort4*)&A_hi[ob] = h4;
    *(ushort4*)&A_lo[ob] = l4;
}

// layer 3: gather tmp10 (width 10, 2 MB -> L2-resident), *inv_in + bias -> d_out
__global__ void k_agg10_epi(const float* __restrict__ tmp, const int* __restrict__ ecsbuf,
                            const int* __restrict__ srcs, const float* __restrict__ inv_in,
                            const float* __restrict__ bias, float* __restrict__ out) {
    int idx = blockIdx.x * 256 + threadIdx.x;
    if (idx >= N_NODES * 5) return;
    int n = idx / 5;
    int f2 = idx - n * 5;
    const float2* tb = (const float2*)(tmp) + f2;
    float ax = 0.f, ay = 0.f;
    int e = ecsbuf[n + 1], end = ecsbuf[n + 2];
    for (; e + 1 < end; e += 2) {
        float2 v0 = tb[srcs[e] * 5];
        float2 v1 = tb[srcs[e + 1] * 5];
        ax += v0.x + v1.x;
        ay += v0.y + v1.y;
    }
    if (e < end) {
        float2 v0 = tb[srcs[e] * 5];
        ax += v0.x;
        ay += v0.y;
    }
    float si = inv_in[n];
    float2 o;
    o.x = ax * si + bias[f2 * 2];
    o.y = ay * si + bias[f2 * 2 + 1];
    *(float2*)&out[n * 10 + f2 * 2] = o;
}

// ---------------- MFMA split-bf16 GEMM, 2 row-tiles per wave ----------------
// D = A@W via A_hi*W_hi + A_hi*W_lo + A_lo*W_hi (~fp32 precision).
// Wave computes 32 rows (two 16-row tiles) sharing B fragments.
// !FUSE_W3 epilogue stores hbuf as fp16 (halves gather bytes of next layer).
// FUSE_W3 (layer 2): h2 never touches memory — per col-tile accumulate
// p10[r][j] += h2 * W3[col][j], 4-step shfl_xor tree over the 16 lanes of each
// row, lane lrow==0 stores tmp[row*10..]. Halves processed sequentially
// (acc0's 4 rows then acc1's) to cap live registers at ~40 over the acc array.
template <int KSTEPS, int LDA, bool FUSE_W3>
__global__ __launch_bounds__(256) void k_gemm_mfma(const unsigned short* __restrict__ A_hi,
                                                   const unsigned short* __restrict__ A_lo,
                                                   const unsigned short* __restrict__ WT_hi,
                                                   const unsigned short* __restrict__ WT_lo,
                                                   const float* __restrict__ bias,
                                                   const float* __restrict__ post,
                                                   _Float16* __restrict__ out,
                                                   const float* __restrict__ W3,
                                                   float* __restrict__ tmp) {
    int tid = threadIdx.x;
    int l = tid & 63, w = tid >> 6;
    int lrow = l & 15, q = l >> 4;
    int rt = blockIdx.x * 128 + w * 32;

    const unsigned short* pa0h = A_hi + (size_t)(rt + lrow) * LDA + q * 8;
    const unsigned short* pa0l = A_lo + (size_t)(rt + lrow) * LDA + q * 8;
    const unsigned short* pa1h = pa0h + 16 * LDA;
    const unsigned short* pa1l = pa0l + 16 * LDA;

    f32x4 acc0[14], acc1[14];
#pragma unroll
    for (int ct = 0; ct < 14; ++ct) {
        acc0[ct] = (f32x4){0.f, 0.f, 0.f, 0.f};
        acc1[ct] = (f32x4){0.f, 0.f, 0.f, 0.f};
    }

#pragma unroll
    for (int ks = 0; ks < KSTEPS; ++ks) {
        int k0 = ks * 32;
        short8 ah0 = *(const short8*)(const void*)(pa0h + k0);
        short8 al0 = *(const short8*)(const void*)(pa0l + k0);
        short8 ah1 = *(const short8*)(const void*)(pa1h + k0);
        short8 al1 = *(const short8*)(const void*)(pa1l + k0);
#pragma unroll
        for (int ct = 0; ct < 14; ++ct) {
            size_t boff = (size_t)(ct * 16 + lrow) * LDA + q * 8 + k0;
            short8 bh = *(const short8*)(const void*)(WT_hi + boff);
            short8 bl = *(const short8*)(const void*)(WT_lo + boff);
            acc0[ct] = mfma16(ah0, bh, acc0[ct]);
            acc0[ct] = mfma16(ah0, bl, acc0[ct]);
            acc0[ct] = mfma16(al0, bh, acc0[ct]);
            acc1[ct] = mfma16(ah1, bh, acc1[ct]);
            acc1[ct] = mfma16(ah1, bl, acc1[ct]);
            acc1[ct] = mfma16(al1, bh, acc1[ct]);
        }
    }

    float pv0[4], pv1[4];
#pragma unroll
    for (int r = 0; r < 4; ++r) {
        int r0 = rt + q * 4 + r;
        int r1 = r0 + 16;
        pv0[r] = (r0 < N_NODES) ? post[r0] : 0.f;
        pv1[r] = (r1 < N_NODES) ? post[r1] : 0.f;
    }

    if (!FUSE_W3) {
#pragma unroll
        for (int ct = 0; ct < 14; ++ct) {
            int col = ct * 16 + lrow;
            if (col >= 220) continue;
            float bv = bias[col];
#pragma unroll
            for (int r = 0; r < 4; ++r) {
                int r0 = rt + q * 4 + r;
                int r1 = r0 + 16;
                if (r0 < N_NODES)
                    out[(size_t)r0 * HSTR + col] = (_Float16)(pv0[r] * fast_tanh(acc0[ct][r] + bv));
                if (r1 < N_NODES)
                    out[(size_t)r1 * HSTR + col] = (_Float16)(pv1[r] * fast_tanh(acc1[ct][r] + bv));
            }
        }
    } else {
#pragma unroll
        for (int half = 0; half < 2; ++half) {
            const f32x4* acc = half ? acc1 : acc0;
            const float* pv  = half ? pv1 : pv0;
            int rbase = rt + half * 16;
            float p[4][10];
#pragma unroll
            for (int r = 0; r < 4; ++r)
#pragma unroll
                for (int j = 0; j < 10; ++j) p[r][j] = 0.f;
#pragma unroll
            for (int ct = 0; ct < 14; ++ct) {
                int col = ct * 16 + lrow;
                bool cok = col < 220;
                float bv = cok ? bias[col] : 0.f;
                float w3v[10];
                if (cok) {
                    const float2* wp = (const float2*)&W3[col * 10];
#pragma unroll
                    for (int j2 = 0; j2 < 5; ++j2) {
                        float2 t = wp[j2];
                        w3v[2 * j2] = t.x;
                        w3v[2 * j2 + 1] = t.y;
                    }
                } else {
#pragma unroll
                    for (int j = 0; j < 10; ++j) w3v[j] = 0.f;
                }
#pragma unroll
                for (int r = 0; r < 4; ++r) {
                    float h2 = pv[r] * fast_tanh(acc[ct][r] + bv);
#pragma unroll
                    for (int j = 0; j < 10; ++j) p[r][j] += h2 * w3v[j];
                }
            }
            // reduce over the 16 lanes (same q) sharing each row
#pragma unroll
            for (int r = 0; r < 4; ++r)
#pragma unroll
                for (int j = 0; j < 10; ++j) {
                    float v = p[r][j];
                    v += __shfl_xor(v, 1, 64);
                    v += __shfl_xor(v, 2, 64);
                    v += __shfl_xor(v, 4, 64);
                    v += __shfl_xor(v, 8, 64);
                    p[r][j] = v;
                }
            if (lrow == 0) {
#pragma unroll
                for (int r = 0; r < 4; ++r) {
                    int row = rbase + q * 4 + r;
                    if (row < N_NODES) {
#pragma unroll
                        for (int j2 = 0; j2 < 5; ++j2) {
                            float2 o = {p[r][2 * j2], p[r][2 * j2 + 1]};
                            *(float2*)&tmp[(size_t)row * 10 + 2 * j2] = o;
                        }
                    }
                }
            }
        }
    }
}

// ---------------- launch ----------------

extern "C" void kernel_launch(void* const* d_in, const int* in_sizes, int n_in,
                              void* d_out, int out_size, void* d_ws, size_t ws_size,
                              hipStream_t stream) {
    const float* x  = (const float*)d_in[0];
    const float* W0 = (const float*)d_in[1];
    const float* b0 = (const float*)d_in[2];
    const float* W1 = (const float*)d_in[3];
    const float* b1 = (const float*)d_in[4];
    const float* W2 = (const float*)d_in[5];
    const float* b2 = (const float*)d_in[6];
    const float* W3 = (const float*)d_in[7];
    const float* b3 = (const float*)d_in[8];
    const int*   ei = (const int*)d_in[9];
    float* out = (float*)d_out;

    int* ws = (int*)d_ws;
    // word offsets (wt1/wt2 = 224*224 ushorts = 25088 WORDS each)
    int* ecsbuf     = ws + 0;               // 50432 (50178 used; [0]=0)
    int* deg_out    = ws + 50432;           // 50176
    int* bsumA      = ws + 100608;          // 256 (196 used)
    float* inv_out  = (float*)(ws + 100864);
    float* inv_in   = (float*)(ws + 151040);
    int* src_sorted = ws + 201216;          // 800000
    unsigned short* wt0h = (unsigned short*)(ws + 1001216);   // 3584 w
    unsigned short* wt0l = (unsigned short*)(ws + 1004800);   // 3584 w
    unsigned short* wt1h = (unsigned short*)(ws + 1008384);   // 25088 w
    unsigned short* wt1l = (unsigned short*)(ws + 1033472);   // 25088 w
    unsigned short* wt2h = (unsigned short*)(ws + 1058560);   // 25088 w
    unsigned short* wt2l = (unsigned short*)(ws + 1083648);   // 25088 w
    unsigned short* ahi  = (unsigned short*)(ws + 1108736);   // 5619712 w
    unsigned short* alo  = (unsigned short*)(ws + 6728448);   // 5619712 w
    _Float16* hbuf = (_Float16*)(ws + 12348160); // 50000*224 halfs = 5600000 w
    float* tmp10 = (float*)(ws + 23548160); // 500000 w -> end 24048160 (96.2 MB)
    // aliases inside ahi (ahi not yet live at those times):
    int* rank    = (int*)ahi;                           // [0, 800000) words of ahi slot
    float* xs    = (float*)(ws + 1108736 + 3000000);    // clear of rank & A22 region

    // zero ecsbuf + deg_out (contiguous)
    hipMemsetAsync(ws, 0, (size_t)100608 * sizeof(int), stream);

    // CSR hist(+rank) fused with weight splits
    k_hist_wsplit<<<3545, 256, 0, stream>>>(ei, deg_out, ecsbuf, rank,
                                            W0, W1, W2, wt0h, wt0l, wt1h, wt1l, wt2h, wt2l);
    k_scan1<<<196, 256, 0, stream>>>(ecsbuf + 1, ecsbuf + 1, bsumA, NPAD);
    k_scan_mid<<<1, 256, 0, stream>>>(bsumA, 196);
    k_scan3<<<196, 256, 0, stream>>>(ecsbuf + 1, bsumA, NPAD);
    k_post_scan<<<5470, 256, 0, stream>>>(ei, ecsbuf, rank, deg_out, x,
                                          inv_out, inv_in, src_sorted, xs);

    int gemm_grid = (NPAD + 127) / 128;      // 392
    int agg_grid  = (N_NODES + 3) / 4;       // 12500

    // ---- layer 0
    k_agg22_split<<<(N_NODES * 16 + 255) / 256, 256, 0, stream>>>(
        xs, ecsbuf, src_sorted, inv_in, ahi, alo);
    k_gemm_mfma<1, 32, false><<<gemm_grid, 256, 0, stream>>>(
        ahi, alo, wt0h, wt0l, b0, inv_out, hbuf, nullptr, nullptr);

    // ---- layer 1
    k_agg220_split<<<agg_grid, 256, 0, stream>>>(hbuf, ecsbuf, src_sorted, inv_in, ahi, alo);
    k_gemm_mfma<7, 224, false><<<gemm_grid, 256, 0, stream>>>(
        ahi, alo, wt1h, wt1l, b1, inv_out, hbuf, nullptr, nullptr);

    // ---- layer 2 (+ fused W3 projection; h2 never materialized)
    k_agg220_split<<<agg_grid, 256, 0, stream>>>(hbuf, ecsbuf, src_sorted, inv_in, ahi, alo);
    k_gemm_mfma<7, 224, true><<<gemm_grid, 256, 0, stream>>>(
        ahi, alo, wt2h, wt2l, b2, inv_out, nullptr, W3, tmp10);

    // ---- layer 3
    k_agg10_epi<<<(N_NODES * 5 + 255) / 256, 256, 0, stream>>>(
        tmp10, ecsbuf, src_sorted, inv_in, b3, out);
}

// Round 3
// 465.761 us; speedup vs baseline: 1.1927x; 1.0047x over previous
//
#include <hip/hip_runtime.h>
#include <math.h>

#define N_NODES 50000
#define N_EDGES 800000
#define NPAD 50176
#define HSTR 224   // hbuf row stride in HALFS: 448 B = exactly 4 x 128B sectors per row fetch
// ecsbuf (NPAD+2 ints, ecsbuf[0]=0): counts at ecsbuf[1+d] (k_hist); post-scan
// ecsbuf[1+d] = start(d), never mutated again (rank-based fill).
// Readers: start(n) = ecsbuf[n+1], end(n) = ecsbuf[n+2].

typedef __attribute__((ext_vector_type(8))) short short8;
typedef __attribute__((ext_vector_type(4))) float f32x4;
typedef __attribute__((ext_vector_type(4))) _Float16 half4;

// ---------------- helpers ----------------

__device__ __forceinline__ float fast_tanh(float x) {
    float e = __expf(2.0f * x);
    float r = __builtin_amdgcn_rcpf(e + 1.0f);
    return 1.0f - 2.0f * r;
}

__device__ __forceinline__ unsigned short rne_bf16(float x) {
    unsigned u = __builtin_bit_cast(unsigned, x);
    return (unsigned short)((u + 0x7FFFu + ((u >> 16) & 1u)) >> 16);
}

__device__ __forceinline__ void split_bf16(float x, unsigned short& hi, unsigned short& lo) {
    hi = rne_bf16(x);
    float hf = __builtin_bit_cast(float, (unsigned)hi << 16);
    lo = rne_bf16(x - hf);
}

__device__ __forceinline__ f32x4 mfma16(short8 a, short8 b, f32x4 c) {
    return __builtin_amdgcn_mfma_f32_16x16x32_bf16(a, b, c, 0, 0, 0);
}

__device__ __forceinline__ void wsplit_one(const float* __restrict__ W, int KIN, int LDA,
                                           unsigned short* __restrict__ WT_hi,
                                           unsigned short* __restrict__ WT_lo, int idx) {
    int n = idx / LDA;
    int k = idx - n * LDA;
    float v = (n < 220 && k < KIN) ? W[k * 220 + n] : 0.f;
    unsigned short hi, lo;
    split_bf16(v, hi, lo);
    WT_hi[idx] = hi;
    WT_lo[idx] = lo;
}

// ---------------- CSR build ----------------

// partitioned launch: [0,3125) histogram + per-edge rank; [3125,3545) weight splits
__global__ void k_hist_wsplit(const int* __restrict__ ei, int* __restrict__ deg_out,
                              int* __restrict__ ecsbuf, int* __restrict__ rank,
                              const float* __restrict__ W0, const float* __restrict__ W1,
                              const float* __restrict__ W2,
                              unsigned short* __restrict__ wt0h, unsigned short* __restrict__ wt0l,
                              unsigned short* __restrict__ wt1h, unsigned short* __restrict__ wt1l,
                              unsigned short* __restrict__ wt2h, unsigned short* __restrict__ wt2l) {
    int bx = blockIdx.x;
    if (bx < 3125) {
        int e = bx * 256 + threadIdx.x;
        if (e < N_EDGES) {
            atomicAdd(&deg_out[ei[e]], 1);
            rank[e] = atomicAdd(&ecsbuf[1 + ei[N_EDGES + e]], 1);
        }
    } else if (bx < 3153) {
        int idx = (bx - 3125) * 256 + threadIdx.x;          // 224*32 = 7168
        if (idx < 224 * 32) wsplit_one(W0, 22, 32, wt0h, wt0l, idx);
    } else if (bx < 3349) {
        int idx = (bx - 3153) * 256 + threadIdx.x;          // 224*224 = 50176
        wsplit_one(W1, 220, 224, wt1h, wt1l, idx);
    } else {
        int idx = (bx - 3349) * 256 + threadIdx.x;
        wsplit_one(W2, 220, 224, wt2h, wt2l, idx);
    }
}

__global__ void k_scan1(const int* __restrict__ in, int* __restrict__ out,
                        int* __restrict__ bsum, int n) {
    __shared__ int s[256];
    int i = blockIdx.x * 256 + threadIdx.x;
    int v = (i < n) ? in[i] : 0;
    s[threadIdx.x] = v;
    __syncthreads();
    for (int off = 1; off < 256; off <<= 1) {
        int t = (threadIdx.x >= off) ? s[threadIdx.x - off] : 0;
        __syncthreads();
        s[threadIdx.x] += t;
        __syncthreads();
    }
    if (i < n) out[i] = s[threadIdx.x] - v;   // exclusive
    if (threadIdx.x == 255 && bsum) bsum[blockIdx.x] = s[255];
}

__global__ void k_scan_mid(int* __restrict__ a, int n) {
    __shared__ int s[256];
    __shared__ int carry;
    if (threadIdx.x == 0) carry = 0;
    for (int base = 0; base < n; base += 256) {
        int i = base + threadIdx.x;
        int v = (i < n) ? a[i] : 0;
        s[threadIdx.x] = v;
        __syncthreads();
        for (int off = 1; off < 256; off <<= 1) {
            int t = (threadIdx.x >= off) ? s[threadIdx.x - off] : 0;
            __syncthreads();
            s[threadIdx.x] += t;
            __syncthreads();
        }
        int c = carry;
        if (i < n) a[i] = s[threadIdx.x] - v + c;
        __syncthreads();
        if (threadIdx.x == 0) carry = c + s[255];
        __syncthreads();
    }
}

__global__ void k_scan3(int* __restrict__ out, const int* __restrict__ bscan, int n) {
    int i = blockIdx.x * 256 + threadIdx.x;
    if (i < n) out[i] += bscan[blockIdx.x];
}

// fused post-scan: [0,196) invsqrt | [196,3321) atomic-free fill | [3321,5470) prescale xs
__global__ void k_post_scan(const int* __restrict__ ei, const int* __restrict__ ecsbuf,
                            const int* __restrict__ rank, const int* __restrict__ deg_out,
                            const float* __restrict__ x,
                            float* __restrict__ inv_out, float* __restrict__ inv_in,
                            int* __restrict__ src_sorted, float* __restrict__ xs) {
    int bx = blockIdx.x;
    if (bx < 196) {
        int n = bx * 256 + threadIdx.x;
        if (n >= N_NODES) return;
        int di = ecsbuf[n + 2] - ecsbuf[n + 1];
        int a = deg_out[n]; if (a < 1) a = 1;
        if (di < 1) di = 1;
        inv_out[n] = 1.0f / sqrtf((float)a);
        inv_in[n]  = 1.0f / sqrtf((float)di);
    } else if (bx < 3321) {
        int e = (bx - 196) * 256 + threadIdx.x;
        if (e < N_EDGES) {
            int d = ei[N_EDGES + e];
            src_sorted[ecsbuf[1 + d] + rank[e]] = ei[e];
        }
    } else {
        int idx = (bx - 3321) * 256 + threadIdx.x;   // n*11 + f2
        if (idx >= N_NODES * 11) return;
        int n = idx / 11;
        int f2 = idx - n * 11;
        int a = deg_out[n]; if (a < 1) a = 1;
        float sc = 1.0f / sqrtf((float)a);
        float2 v = *(const float2*)&x[n * 22 + f2 * 2];
        v.x *= sc; v.y *= sc;
        *(float2*)&xs[n * 22 + f2 * 2] = v;
    }
}

// ---------------- aggregation ----------------

// layer 0: gather pre-scaled xs (width 22), *inv_in, split to bf16 A (K pad 32).
__global__ void k_agg22_split(const float* __restrict__ xs,
                              const int* __restrict__ ecsbuf, const int* __restrict__ srcs,
                              const float* __restrict__ inv_in,
                              unsigned short* __restrict__ A_hi, unsigned short* __restrict__ A_lo) {
    int idx = blockIdx.x * 256 + threadIdx.x;
    int n = idx >> 4, f2 = idx & 15;
    if (n >= N_NODES) return;
    float ax = 0.f, ay = 0.f;
    if (f2 <= 10) {
        const float2* xb = (const float2*)(xs) + f2;
        int e = ecsbuf[n + 1], end = ecsbuf[n + 2];
        for (; e + 3 < end; e += 4) {
            int s0 = srcs[e], s1 = srcs[e + 1], s2 = srcs[e + 2], s3 = srcs[e + 3];
            float2 v0 = xb[s0 * 11], v1 = xb[s1 * 11];
            float2 v2 = xb[s2 * 11], v3 = xb[s3 * 11];
            ax += (v0.x + v1.x) + (v2.x + v3.x);
            ay += (v0.y + v1.y) + (v2.y + v3.y);
        }
        for (; e < end; ++e) {
            float2 v0 = xb[srcs[e] * 11];
            ax += v0.x;
            ay += v0.y;
        }
        float si = inv_in[n];
        ax *= si; ay *= si;
    }
    ushort2 h2, l2;
    split_bf16(ax, h2.x, l2.x);
    split_bf16(ay, h2.y, l2.y);
    *(ushort2*)&A_hi[n * 32 + f2 * 2] = h2;
    *(ushort2*)&A_lo[n * 32 + f2 * 2] = l2;
}

// width-220 gather (h stored fp16, row = 224 halfs = 448 B = 4 sectors) + *inv_in
// -> split bf16 A.  One node per 64-lane group; lanes 0..54 own 4 features
// (8 B half4 loads); 8 loads in flight; fp32 accumulation.
__global__ __launch_bounds__(256) void k_agg220_split(const _Float16* __restrict__ h,
                                                      const int* __restrict__ ecsbuf,
                                                      const int* __restrict__ srcs,
                                                      const float* __restrict__ inv_in,
                                                      unsigned short* __restrict__ A_hi,
                                                      unsigned short* __restrict__ A_lo) {
    int lane = threadIdx.x & 63;
    int n = blockIdx.x * 4 + (threadIdx.x >> 6);
    if (n >= N_NODES || lane >= 56) return;   // no barriers; early-exit safe
    size_t ob = (size_t)n * 224 + lane * 4;
    if (lane == 55) {                          // K-pad columns 220..223 = 0
        ushort4 z = {0, 0, 0, 0};
        *(ushort4*)&A_hi[ob] = z;
        *(ushort4*)&A_lo[ob] = z;
        return;
    }
    int f4 = lane * 4;
    const _Float16* hb = h + f4;
    int e = ecsbuf[n + 1], end = ecsbuf[n + 2];
    float4 a0 = {0,0,0,0}, a1 = {0,0,0,0}, a2 = {0,0,0,0}, a3 = {0,0,0,0};
    for (; e + 7 < end; e += 8) {
        int s0 = srcs[e],     s1 = srcs[e + 1], s2 = srcs[e + 2], s3 = srcs[e + 3];
        int s4 = srcs[e + 4], s5 = srcs[e + 5], s6 = srcs[e + 6], s7 = srcs[e + 7];
        half4 v0 = *(const half4*)(hb + (size_t)s0 * HSTR);
        half4 v1 = *(const half4*)(hb + (size_t)s1 * HSTR);
        half4 v2 = *(const half4*)(hb + (size_t)s2 * HSTR);
        half4 v3 = *(const half4*)(hb + (size_t)s3 * HSTR);
        half4 v4 = *(const half4*)(hb + (size_t)s4 * HSTR);
        half4 v5 = *(const half4*)(hb + (size_t)s5 * HSTR);
        half4 v6 = *(const half4*)(hb + (size_t)s6 * HSTR);
        half4 v7 = *(const half4*)(hb + (size_t)s7 * HSTR);
        a0.x += (float)v0.x; a0.y += (float)v0.y; a0.z += (float)v0.z; a0.w += (float)v0.w;
        a1.x += (float)v1.x; a1.y += (float)v1.y; a1.z += (float)v1.z; a1.w += (float)v1.w;
        a2.x += (float)v2.x; a2.y += (float)v2.y; a2.z += (float)v2.z; a2.w += (float)v2.w;
        a3.x += (float)v3.x; a3.y += (float)v3.y; a3.z += (float)v3.z; a3.w += (float)v3.w;
        a0.x += (float)v4.x; a0.y += (float)v4.y; a0.z += (float)v4.z; a0.w += (float)v4.w;
        a1.x += (float)v5.x; a1.y += (float)v5.y; a1.z += (float)v5.z; a1.w += (float)v5.w;
        a2.x += (float)v6.x; a2.y += (float)v6.y; a2.z += (float)v6.z; a2.w += (float)v6.w;
        a3.x += (float)v7.x; a3.y += (float)v7.y; a3.z += (float)v7.z; a3.w += (float)v7.w;
    }
    for (; e + 3 < end; e += 4) {
        int s0 = srcs[e], s1 = srcs[e + 1], s2 = srcs[e + 2], s3 = srcs[e + 3];
        half4 v0 = *(const half4*)(hb + (size_t)s0 * HSTR);
        half4 v1 = *(const half4*)(hb + (size_t)s1 * HSTR);
        half4 v2 = *(const half4*)(hb + (size_t)s2 * HSTR);
        half4 v3 = *(const half4*)(hb + (size_t)s3 * HSTR);
        a0.x += (float)v0.x; a0.y += (float)v0.y; a0.z += (float)v0.z; a0.w += (float)v0.w;
        a1.x += (float)v1.x; a1.y += (float)v1.y; a1.z += (float)v1.z; a1.w += (float)v1.w;
        a2.x += (float)v2.x; a2.y += (float)v2.y; a2.z += (float)v2.z; a2.w += (float)v2.w;
        a3.x += (float)v3.x; a3.y += (float)v3.y; a3.z += (float)v3.z; a3.w += (float)v3.w;
    }
    for (; e < end; ++e) {
        half4 v = *(const half4*)(hb + (size_t)srcs[e] * HSTR);
        a0.x += (float)v.x; a0.y += (float)v.y; a0.z += (float)v.z; a0.w += (float)v.w;
    }
    float sc = inv_in[n];
    float4 t;
    t.x = ((a0.x + a1.x) + (a2.x + a3.x)) * sc;
    t.y = ((a0.y + a1.y) + (a2.y + a3.y)) * sc;
    t.z = ((a0.z + a1.z) + (a2.z + a3.z)) * sc;
    t.w = ((a0.w + a1.w) + (a2.w + a3.w)) * sc;
    ushort4 h4, l4;
    split_bf16(t.x, h4.x, l4.x);
    split_bf16(t.y, h4.y, l4.y);
    split_bf16(t.z, h4.z, l4.z);
    split_bf16(t.w, h4.w, l4.w);
    *(ushort4*)&A_hi[ob] = h4;
    *(ushort4*)&A_lo[ob] = l4;
}

// layer 3: gather tmp10 (width 10, 2 MB -> L2-resident), *inv_in + bias -> d_out
__global__ void k_agg10_epi(const float* __restrict__ tmp, const int* __restrict__ ecsbuf,
                            const int* __restrict__ srcs, const float* __restrict__ inv_in,
                            const float* __restrict__ bias, float* __restrict__ out) {
    int idx = blockIdx.x * 256 + threadIdx.x;
    if (idx >= N_NODES * 5) return;
    int n = idx / 5;
    int f2 = idx - n * 5;
    const float2* tb = (const float2*)(tmp) + f2;
    float ax = 0.f, ay = 0.f;
    int e = ecsbuf[n + 1], end = ecsbuf[n + 2];
    for (; e + 1 < end; e += 2) {
        float2 v0 = tb[srcs[e] * 5];
        float2 v1 = tb[srcs[e + 1] * 5];
        ax += v0.x + v1.x;
        ay += v0.y + v1.y;
    }
    if (e < end) {
        float2 v0 = tb[srcs[e] * 5];
        ax += v0.x;
        ay += v0.y;
    }
    float si = inv_in[n];
    float2 o;
    o.x = ax * si + bias[f2 * 2];
    o.y = ay * si + bias[f2 * 2 + 1];
    *(float2*)&out[n * 10 + f2 * 2] = o;
}

// ---------------- MFMA split-bf16 GEMM, LDS-staged B, 2 row-tiles per wave ----
// D = A@W via A_hi*W_hi + A_hi*W_lo + A_lo*W_hi (~fp32 precision).
// B (wt hi+lo) K-slice [224 rows x 32 cols] staged in LDS per block, double
// buffered; one barrier per K-step. LDS row layout: hi[32] lo[32] interleaved,
// row stride 72 ushorts (144 B, 16B-aligned): ds_read_b128/ds_write_b128 hit
// every bank exactly 8x (the minimum) -> conflict-free. Buffer parity proof:
// iter k reads buf[k&1]; iter k+1 writes buf[k&1]; separated by end-of-iter-k
// __syncthreads.
// Wave computes 32 rows (two 16-row tiles) sharing B fragments.
// !FUSE_W3 epilogue stores hbuf as fp16 (halves gather bytes of next layer).
// FUSE_W3 (layer 2): h2 never touches memory — per col-tile accumulate
// p10[r][j] += h2 * W3[col][j], 4-step shfl_xor tree over the 16 lanes of each
// row, lane lrow==0 stores tmp[row*10..].
template <int KSTEPS, int LDA, bool FUSE_W3>
__global__ __launch_bounds__(256) void k_gemm_mfma(const unsigned short* __restrict__ A_hi,
                                                   const unsigned short* __restrict__ A_lo,
                                                   const unsigned short* __restrict__ WT_hi,
                                                   const unsigned short* __restrict__ WT_lo,
                                                   const float* __restrict__ bias,
                                                   const float* __restrict__ post,
                                                   _Float16* __restrict__ out,
                                                   const float* __restrict__ W3,
                                                   float* __restrict__ tmp) {
    __shared__ unsigned short Bs[2][224 * 72];   // 64,512 B

    int tid = threadIdx.x;
    int l = tid & 63, w = tid >> 6;
    int lrow = l & 15, q = l >> 4;
    int rt = blockIdx.x * 128 + w * 32;

    const unsigned short* pa0h = A_hi + (size_t)(rt + lrow) * LDA + q * 8;
    const unsigned short* pa0l = A_lo + (size_t)(rt + lrow) * LDA + q * 8;
    const unsigned short* pa1h = pa0h + 16 * LDA;
    const unsigned short* pa1l = pa0l + 16 * LDA;

    // staging chunk map: f = tid + 256*i, i<7; r = f>>3 (row), j = f&7
    // (j<4: hi cols j*8 ; j>=4: lo cols (j-4)*8). 1792 chunks = 224 rows * 8.
    int sr[7], sjl[7], sjo[7];
#pragma unroll
    for (int i = 0; i < 7; ++i) {
        int f = tid + 256 * i;
        sr[i] = f >> 3;
        int j = f & 7;
        sjl[i] = (j & 3) * 8;                 // col offset within 32
        sjo[i] = (j >> 2);                    // 0 = hi, 1 = lo
    }

    // prologue: stage k-slice 0 into buf 0
    {
        short8 sreg[7];
#pragma unroll
        for (int i = 0; i < 7; ++i) {
            const unsigned short* g = (sjo[i] ? WT_lo : WT_hi) + (size_t)sr[i] * LDA + sjl[i];
            sreg[i] = *(const short8*)(const void*)g;
        }
#pragma unroll
        for (int i = 0; i < 7; ++i)
            *(short8*)(void*)&Bs[0][sr[i] * 72 + sjo[i] * 32 + sjl[i]] = sreg[i];
    }
    __syncthreads();

    f32x4 acc0[14], acc1[14];
#pragma unroll
    for (int ct = 0; ct < 14; ++ct) {
        acc0[ct] = (f32x4){0.f, 0.f, 0.f, 0.f};
        acc1[ct] = (f32x4){0.f, 0.f, 0.f, 0.f};
    }

    int bro = lrow * 72 + q * 8;   // base read offset within a ct-tile

#pragma unroll
    for (int ks = 0; ks < KSTEPS; ++ks) {
        int cur = ks & 1;
        bool has_next = (ks + 1 < KSTEPS);

        // issue next k-slice global loads early (latency hidden by MFMAs below)
        short8 sreg[7];
        if (has_next) {
            int k0n = (ks + 1) * 32;
#pragma unroll
            for (int i = 0; i < 7; ++i) {
                const unsigned short* g = (sjo[i] ? WT_lo : WT_hi) + (size_t)sr[i] * LDA + k0n + sjl[i];
                sreg[i] = *(const short8*)(const void*)g;
            }
        }

        int k0 = ks * 32;
        short8 ah0 = *(const short8*)(const void*)(pa0h + k0);
        short8 al0 = *(const short8*)(const void*)(pa0l + k0);
        short8 ah1 = *(const short8*)(const void*)(pa1h + k0);
        short8 al1 = *(const short8*)(const void*)(pa1l + k0);

#pragma unroll
        for (int ct = 0; ct < 14; ++ct) {
            const unsigned short* bp = &Bs[cur][ct * 1152 + bro];
            short8 bh = *(const short8*)(const void*)bp;
            short8 bl = *(const short8*)(const void*)(bp + 32);
            acc0[ct] = mfma16(ah0, bh, acc0[ct]);
            acc0[ct] = mfma16(ah0, bl, acc0[ct]);
            acc0[ct] = mfma16(al0, bh, acc0[ct]);
            acc1[ct] = mfma16(ah1, bh, acc1[ct]);
            acc1[ct] = mfma16(ah1, bl, acc1[ct]);
            acc1[ct] = mfma16(al1, bh, acc1[ct]);
        }

        if (has_next) {
#pragma unroll
            for (int i = 0; i < 7; ++i)
                *(short8*)(void*)&Bs[1 - cur][sr[i] * 72 + sjo[i] * 32 + sjl[i]] = sreg[i];
            __syncthreads();
        }
    }

    float pv0[4], pv1[4];
#pragma unroll
    for (int r = 0; r < 4; ++r) {
        int r0 = rt + q * 4 + r;
        int r1 = r0 + 16;
        pv0[r] = (r0 < N_NODES) ? post[r0] : 0.f;
        pv1[r] = (r1 < N_NODES) ? post[r1] : 0.f;
    }

    if (!FUSE_W3) {
#pragma unroll
        for (int ct = 0; ct < 14; ++ct) {
            int col = ct * 16 + lrow;
            if (col >= 220) continue;
            float bv = bias[col];
#pragma unroll
            for (int r = 0; r < 4; ++r) {
                int r0 = rt + q * 4 + r;
                int r1 = r0 + 16;
                if (r0 < N_NODES)
                    out[(size_t)r0 * HSTR + col] = (_Float16)(pv0[r] * fast_tanh(acc0[ct][r] + bv));
                if (r1 < N_NODES)
                    out[(size_t)r1 * HSTR + col] = (_Float16)(pv1[r] * fast_tanh(acc1[ct][r] + bv));
            }
        }
    } else {
#pragma unroll
        for (int half = 0; half < 2; ++half) {
            const f32x4* acc = half ? acc1 : acc0;
            const float* pv  = half ? pv1 : pv0;
            int rbase = rt + half * 16;
            float p[4][10];
#pragma unroll
            for (int r = 0; r < 4; ++r)
#pragma unroll
                for (int j = 0; j < 10; ++j) p[r][j] = 0.f;
#pragma unroll
            for (int ct = 0; ct < 14; ++ct) {
                int col = ct * 16 + lrow;
                bool cok = col < 220;
                float bv = cok ? bias[col] : 0.f;
                float w3v[10];
                if (cok) {
                    const float2* wp = (const float2*)&W3[col * 10];
#pragma unroll
                    for (int j2 = 0; j2 < 5; ++j2) {
                        float2 t = wp[j2];
                        w3v[2 * j2] = t.x;
                        w3v[2 * j2 + 1] = t.y;
                    }
                } else {
#pragma unroll
                    for (int j = 0; j < 10; ++j) w3v[j] = 0.f;
                }
#pragma unroll
                for (int r = 0; r < 4; ++r) {
                    float h2 = pv[r] * fast_tanh(acc[ct][r] + bv);
#pragma unroll
                    for (int j = 0; j < 10; ++j) p[r][j] += h2 * w3v[j];
                }
            }
            // reduce over the 16 lanes (same q) sharing each row
#pragma unroll
            for (int r = 0; r < 4; ++r)
#pragma unroll
                for (int j = 0; j < 10; ++j) {
                    float v = p[r][j];
                    v += __shfl_xor(v, 1, 64);
                    v += __shfl_xor(v, 2, 64);
                    v += __shfl_xor(v, 4, 64);
                    v += __shfl_xor(v, 8, 64);
                    p[r][j] = v;
                }
            if (lrow == 0) {
#pragma unroll
                for (int r = 0; r < 4; ++r) {
                    int row = rbase + q * 4 + r;
                    if (row < N_NODES) {
#pragma unroll
                        for (int j2 = 0; j2 < 5; ++j2) {
                            float2 o = {p[r][2 * j2], p[r][2 * j2 + 1]};
                            *(float2*)&tmp[(size_t)row * 10 + 2 * j2] = o;
                        }
                    }
                }
            }
        }
    }
}

// ---------------- launch ----------------

extern "C" void kernel_launch(void* const* d_in, const int* in_sizes, int n_in,
                              void* d_out, int out_size, void* d_ws, size_t ws_size,
                              hipStream_t stream) {
    const float* x  = (const float*)d_in[0];
    const float* W0 = (const float*)d_in[1];
    const float* b0 = (const float*)d_in[2];
    const float* W1 = (const float*)d_in[3];
    const float* b1 = (const float*)d_in[4];
    const float* W2 = (const float*)d_in[5];
    const float* b2 = (const float*)d_in[6];
    const float* W3 = (const float*)d_in[7];
    const float* b3 = (const float*)d_in[8];
    const int*   ei = (const int*)d_in[9];
    float* out = (float*)d_out;

    int* ws = (int*)d_ws;
    // word offsets (wt1/wt2 = 224*224 ushorts = 25088 WORDS each)
    int* ecsbuf     = ws + 0;               // 50432 (50178 used; [0]=0)
    int* deg_out    = ws + 50432;           // 50176
    int* bsumA      = ws + 100608;          // 256 (196 used)
    float* inv_out  = (float*)(ws + 100864);
    float* inv_in   = (float*)(ws + 151040);
    int* src_sorted = ws + 201216;          // 800000
    unsigned short* wt0h = (unsigned short*)(ws + 1001216);   // 3584 w
    unsigned short* wt0l = (unsigned short*)(ws + 1004800);   // 3584 w
    unsigned short* wt1h = (unsigned short*)(ws + 1008384);   // 25088 w
    unsigned short* wt1l = (unsigned short*)(ws + 1033472);   // 25088 w
    unsigned short* wt2h = (unsigned short*)(ws + 1058560);   // 25088 w
    unsigned short* wt2l = (unsigned short*)(ws + 1083648);   // 25088 w
    unsigned short* ahi  = (unsigned short*)(ws + 1108736);   // 5619712 w
    unsigned short* alo  = (unsigned short*)(ws + 6728448);   // 5619712 w
    _Float16* hbuf = (_Float16*)(ws + 12348160); // 50000*224 halfs = 5600000 w
    float* tmp10 = (float*)(ws + 23548160); // 500000 w -> end 24048160 (96.2 MB)
    // aliases inside ahi (ahi not yet live at those times):
    int* rank    = (int*)ahi;                           // [0, 800000) words of ahi slot
    float* xs    = (float*)(ws + 1108736 + 3000000);    // clear of rank & A22 region

    // zero ecsbuf + deg_out (contiguous)
    hipMemsetAsync(ws, 0, (size_t)100608 * sizeof(int), stream);

    // CSR hist(+rank) fused with weight splits
    k_hist_wsplit<<<3545, 256, 0, stream>>>(ei, deg_out, ecsbuf, rank,
                                            W0, W1, W2, wt0h, wt0l, wt1h, wt1l, wt2h, wt2l);
    k_scan1<<<196, 256, 0, stream>>>(ecsbuf + 1, ecsbuf + 1, bsumA, NPAD);
    k_scan_mid<<<1, 256, 0, stream>>>(bsumA, 196);
    k_scan3<<<196, 256, 0, stream>>>(ecsbuf + 1, bsumA, NPAD);
    k_post_scan<<<5470, 256, 0, stream>>>(ei, ecsbuf, rank, deg_out, x,
                                          inv_out, inv_in, src_sorted, xs);

    int gemm_grid = (NPAD + 127) / 128;      // 392
    int agg_grid  = (N_NODES + 3) / 4;       // 12500

    // ---- layer 0
    k_agg22_split<<<(N_NODES * 16 + 255) / 256, 256, 0, stream>>>(
        xs, ecsbuf, src_sorted, inv_in, ahi, alo);
    k_gemm_mfma<1, 32, false><<<gemm_grid, 256, 0, stream>>>(
        ahi, alo, wt0h, wt0l, b0, inv_out, hbuf, nullptr, nullptr);

    // ---- layer 1
    k_agg220_split<<<agg_grid, 256, 0, stream>>>(hbuf, ecsbuf, src_sorted, inv_in, ahi, alo);
    k_gemm_mfma<7, 224, false><<<gemm_grid, 256, 0, stream>>>(
        ahi, alo, wt1h, wt1l, b1, inv_out, hbuf, nullptr, nullptr);

    // ---- layer 2 (+ fused W3 projection; h2 never materialized)
    k_agg220_split<<<agg_grid, 256, 0, stream>>>(hbuf, ecsbuf, src_sorted, inv_in, ahi, alo);
    k_gemm_mfma<7, 224, true><<<gemm_grid, 256, 0, stream>>>(
        ahi, alo, wt2h, wt2l, b2, inv_out, nullptr, W3, tmp10);

    // ---- layer 3
    k_agg10_epi<<<(N_NODES * 5 + 255) / 256, 256, 0, stream>>>(
        tmp10, ecsbuf, src_sorted, inv_in, b3, out);
}